// Round 18
// baseline (795.585 us; speedup 1.0000x reference)
//
#include <hip/hip_runtime.h>

#define D   80
#define NE  1024
#define HS  128               // embeddings per half-stage
#define NH  (NE / HS)         // 8 half-stages per phase
#define CAP 32
// MARGIN >= 2*delta_bf16 (~0.42 worst case) + |ec-1| drift (~1e-5)
#define MARGIN 0.5f

// ws layout (bytes):
#define OFF_ACC  0            // 64B   double loss accumulator
#define OFF_EN   64           // [NE][D] f32 normalized embed (exact, ref order)
#define OFF_EC   327744       // [NE]    f32 ||en||^2 (exact, ref order)
#define OFF_ENBT 331840       // [10][NE] 16B chunks: bf16(-2*en), chunk-major
#define OFF_CNT  1019968      // [n] int  candidate count per row
#define OFF_LIST 1544256      // [n][CAP] u16 candidate j's
#define WS_NEED  9932864

typedef __attribute__((ext_vector_type(8)))  short bf16x8;
typedef __attribute__((ext_vector_type(4)))  float f32x4;
typedef __attribute__((ext_vector_type(16))) float f32x16;

static __device__ __forceinline__ short f2bf(float f) {   // RNE float->bf16
    unsigned u = __float_as_uint(f);
    return (short)((u + 0x7fffu + ((u >> 16) & 1u)) >> 16);
}

static __device__ __forceinline__ bf16x8 cvt8(const float* p) {
    float4 f0 = *(const float4*)p;
    float4 f1 = *(const float4*)(p + 4);
    bf16x8 a;
    a[0] = f2bf(f0.x); a[1] = f2bf(f0.y); a[2] = f2bf(f0.z); a[3] = f2bf(f0.w);
    a[4] = f2bf(f1.x); a[5] = f2bf(f1.y); a[6] = f2bf(f1.z); a[7] = f2bf(f1.w);
    return a;
}

// direct global->LDS DMA, 16B per lane (zero VGPR staging)
static __device__ __forceinline__ void gload_lds16(const void* g, void* l) {
    __builtin_amdgcn_global_load_lds(
        (const __attribute__((address_space(1))) unsigned int*)g,
        (__attribute__((address_space(3))) unsigned int*)l, 16, 0, 0);
}

// ---------------- prep: exact en/ec (bit-exact ref order) + enbT ------------
// enbT chunk-major: chunk c (bf16 k in [8c,8c+8)) of emb j at c*16384 + j*16.
__global__ __launch_bounds__(256) void vq_prep(const float* __restrict__ w,
                                               float* __restrict__ en,
                                               float* __restrict__ ec,
                                               char* __restrict__ enbT) {
    int j = blockIdx.x * blockDim.x + threadIdx.x;
    if (j >= NE) return;
    const float* wj = w + j * D;
    float s = __fmul_rn(wj[0], wj[0]);
    for (int k = 1; k < D; ++k) s = __fadd_rn(s, __fmul_rn(wj[k], wj[k]));
    float norm = __fsqrt_rn(s);
    float* ej = en + j * D;
    float c = 0.f;
    for (int k = 0; k < D; ++k) {
        float v = __fdiv_rn(wj[k], norm);
        ej[k] = v;
        float sq = __fmul_rn(v, v);
        c = (k == 0) ? sq : __fadd_rn(c, sq);  // sequential k-order like np
    }
    ec[j] = c;
    for (int cc = 0; cc < 10; ++cc) {
        bf16x8 b;
#pragma unroll
        for (int e = 0; e < 8; ++e)
            b[e] = f2bf(__fmul_rn(-2.0f, ej[cc * 8 + e]));
        *(bf16x8*)(enbT + cc * 16384 + j * 16) = b;
    }
}

// ---------------- MFMA filter: two-phase, 32x32x16 (K=80 = 5x16, NO pad) ----
// r18: 16x16x32 (K=96 padded) -> 32x32x16 (K=80 exact). Per 32rows x 32embs:
// 5 MFMA @8.07cy = 40cy vs 12 @4.85 = 58cy; LDS 80B vs 96B per lane.
// A: row=lane&31, k=8*(lane>>5)+e, frag s covers k in [16s,16s+16).
// B: col=lane&31, same k -> chunk (2s + (lane>>5)) of our chunk-major LDS.
// C/D: col=lane&31, row=(reg&3)+8*(reg>>2)+4*(lane>>5)  [guide m74/m101].
__global__ __launch_bounds__(256)
__attribute__((amdgpu_waves_per_eu(4, 4)))
void vq_mfma(
        const float* __restrict__ x,
        const char* __restrict__ enbT,
        int* __restrict__ cnt,
        unsigned short* __restrict__ list,
        int n) {
    __shared__ __align__(16) char lds[2][20480];

    const int tid  = threadIdx.x;
    const int lane = tid & 63;
    const int wv   = tid >> 6;
    const int row0 = blockIdx.x * 128 + wv * 32;   // 32 rows per wave (1 tile)
    const int l31  = lane & 31;
    const int hl   = lane >> 5;

    // A fragments: 5 x K16, covers K=80 exactly (no zero pad needed).
    bf16x8 A[5];
    {
        const float* xr = x + (size_t)(row0 + l31) * D;
#pragma unroll
        for (int s = 0; s < 5; ++s)
            A[s] = cvt8(xr + 16 * s + 8 * hl);
    }

#define STAGE(b, h) do {                                                      \
        _Pragma("unroll")                                                     \
        for (int t = 0; t < 5; ++t) {                                         \
            int slot = tid + t * 256;                                         \
            gload_lds16(enbT + (size_t)(slot >> 7) * 16384 + (h) * 2048       \
                             + (slot & 127) * 16,                             \
                        &lds[b][0] + slot * 16);                              \
        }                                                                     \
    } while (0)

    float vmin[16];
#pragma unroll
    for (int r = 0; r < 16; ++r) vmin[r] = 3.4e38f;

    // ================= phase A: min-only scan =================
    STAGE(0, 0);
    for (int h = 0; h < NH; ++h) {
        __syncthreads();                 // drains DMA(h); prior reads done
        if (h + 1 < NH) STAGE((h + 1) & 1, h + 1);   // lands during compute
        const char* buf = &lds[h & 1][0];
        for (int e32 = 0; e32 < 4; ++e32) {
            const char* base = buf + (e32 * 32 + l31) * 16;
            bf16x8 B0 = *(const bf16x8*)(base + (0 + hl) * 2048);
            bf16x8 B1 = *(const bf16x8*)(base + (2 + hl) * 2048);
            bf16x8 B2 = *(const bf16x8*)(base + (4 + hl) * 2048);
            bf16x8 B3 = *(const bf16x8*)(base + (6 + hl) * 2048);
            bf16x8 B4 = *(const bf16x8*)(base + (8 + hl) * 2048);
            f32x16 c = {0.f,0.f,0.f,0.f,0.f,0.f,0.f,0.f,
                        0.f,0.f,0.f,0.f,0.f,0.f,0.f,0.f};
            c = __builtin_amdgcn_mfma_f32_32x32x16_bf16(A[0], B0, c, 0, 0, 0);
            c = __builtin_amdgcn_mfma_f32_32x32x16_bf16(A[1], B1, c, 0, 0, 0);
            c = __builtin_amdgcn_mfma_f32_32x32x16_bf16(A[2], B2, c, 0, 0, 0);
            c = __builtin_amdgcn_mfma_f32_32x32x16_bf16(A[3], B3, c, 0, 0, 0);
            c = __builtin_amdgcn_mfma_f32_32x32x16_bf16(A[4], B4, c, 0, 0, 0);
#pragma unroll
            for (int r = 0; r < 16; ++r) vmin[r] = fminf(vmin[r], c[r]);
        }
    }

    // final threshold: reduce across the 32 lanes sharing each output row
    float thr[16];
#pragma unroll
    for (int r = 0; r < 16; ++r) {
        float v = vmin[r];
#pragma unroll
        for (int m = 1; m < 32; m <<= 1) v = fminf(v, __shfl_xor(v, m));
        thr[r] = v + MARGIN;             // xor masks <32 keep lane>>5 fixed
    }

    // ================= phase B: re-scan, capture candidates =================
    STAGE(0, 0);                         // safe: all buf0 phase-A reads done
    for (int h = 0; h < NH; ++h) {
        __syncthreads();
        if (h + 1 < NH) STAGE((h + 1) & 1, h + 1);
        const char* buf = &lds[h & 1][0];
        for (int e32 = 0; e32 < 4; ++e32) {
            const char* base = buf + (e32 * 32 + l31) * 16;
            bf16x8 B0 = *(const bf16x8*)(base + (0 + hl) * 2048);
            bf16x8 B1 = *(const bf16x8*)(base + (2 + hl) * 2048);
            bf16x8 B2 = *(const bf16x8*)(base + (4 + hl) * 2048);
            bf16x8 B3 = *(const bf16x8*)(base + (6 + hl) * 2048);
            bf16x8 B4 = *(const bf16x8*)(base + (8 + hl) * 2048);
            f32x16 c = {0.f,0.f,0.f,0.f,0.f,0.f,0.f,0.f,
                        0.f,0.f,0.f,0.f,0.f,0.f,0.f,0.f};
            c = __builtin_amdgcn_mfma_f32_32x32x16_bf16(A[0], B0, c, 0, 0, 0);
            c = __builtin_amdgcn_mfma_f32_32x32x16_bf16(A[1], B1, c, 0, 0, 0);
            c = __builtin_amdgcn_mfma_f32_32x32x16_bf16(A[2], B2, c, 0, 0, 0);
            c = __builtin_amdgcn_mfma_f32_32x32x16_bf16(A[3], B3, c, 0, 0, 0);
            c = __builtin_amdgcn_mfma_f32_32x32x16_bf16(A[4], B4, c, 0, 0, 0);
            unsigned hm = 0;
#pragma unroll
            for (int r = 0; r < 16; ++r)
                if (c[r] <= thr[r]) hm |= 1u << r;
            if (__any(hm != 0)) {
                int jj = h * HS + e32 * 32 + l31;
#pragma unroll
                for (int r = 0; r < 16; ++r) {
                    if (hm & (1u << r)) {
                        int row = row0 + (r & 3) + 8 * (r >> 2) + 4 * hl;
                        int o = atomicAdd(cnt + row, 1);
                        if (o < CAP)
                            list[(size_t)row * CAP + o] = (unsigned short)jj;
                    }
                }
            }
        }
    }
#undef STAGE
}

// ---------- fused exact + epilogue (r13-proven cfg + r16-proven c==1 path) --
// waves_per_eu(1,2) -> VGPR 88, X[80] resident (r14 lesson: do not touch).
__global__ __launch_bounds__(256)
__attribute__((amdgpu_waves_per_eu(1, 2)))
void vq_exact_epi(const float* __restrict__ x,
                  const float* __restrict__ en,
                  const float* __restrict__ ec,
                  const int* __restrict__ cnt,
                  const unsigned short* __restrict__ list,
                  const float* __restrict__ w,
                  float* __restrict__ out,
                  double* __restrict__ loss_acc, int n) {
    __shared__ int sbidx[256];
    __shared__ double bsum[4];
    const int row = blockIdx.x * 256 + threadIdx.x;

    int bi = 0;
    if (row < n) {
        int c = cnt[row];                       // issue early: gates everything
        if (c == 1) {
            bi = list[(size_t)row * CAP];       // singleton superset == argmin
        } else {
            float X[D];
            const float4* x4 = (const float4*)(x + (size_t)row * D);
#pragma unroll
            for (int i = 0; i < D / 4; ++i) {
                float4 v = x4[i];
                X[4 * i + 0] = v.x; X[4 * i + 1] = v.y;
                X[4 * i + 2] = v.z; X[4 * i + 3] = v.w;
            }
            // A = ||x||^2, numpy pairwise 8-accumulator pattern
            float pr[8];
#pragma unroll
            for (int t = 0; t < 8; ++t) pr[t] = __fmul_rn(X[t], X[t]);
#pragma unroll
            for (int base = 8; base < D; base += 8)
#pragma unroll
                for (int t = 0; t < 8; ++t)
                    pr[t] = __fadd_rn(pr[t], __fmul_rn(X[base + t], X[base + t]));
            float A = __fadd_rn(
                __fadd_rn(__fadd_rn(pr[0], pr[1]), __fadd_rn(pr[2], pr[3])),
                __fadd_rn(__fadd_rn(pr[4], pr[5]), __fadd_rn(pr[6], pr[7])));

            float best = 3.4e38f;
            bi = -1;
            if (c >= 2 && c <= CAP) {
                for (int i = 0; i < c; ++i) {
                    int j = list[(size_t)row * CAP + i];
                    const float* ej = en + j * D;
                    float d = 0.f;
#pragma unroll
                    for (int k = 0; k < D; ++k) d = __builtin_fmaf(X[k], ej[k], d);
                    float s = __fadd_rn(__fsub_rn(A, __fmul_rn(2.0f, d)), ec[j]);
                    // strict < plus lowest-j on exact tie == first-index rule
                    if (s < best || (s == best && j < bi)) { best = s; bi = j; }
                }
            } else {  // overflow / empty (never expected): exact full scan
                for (int j = 0; j < NE; ++j) {
                    const float* ej = en + j * D;
                    float d = 0.f;
#pragma unroll
                    for (int k = 0; k < D; ++k) d = __builtin_fmaf(X[k], ej[k], d);
                    float s = __fadd_rn(__fsub_rn(A, __fmul_rn(2.0f, d)), ec[j]);
                    if (s < best) { best = s; bi = j; }
                }
            }
        }
    }
    sbidx[threadIdx.x] = bi;
    __syncthreads();

    // epilogue: 256 rows cooperative, coalesced (proven r3 pattern)
    const int row0 = blockIdx.x * 256;
    double ss = 0.0;
#pragma unroll
    for (int t = 0; t < 20; ++t) {
        int f  = threadIdx.x + t * 256;        // 5120 = 256 rows x 20 float4
        int rr = f / 20;
        int k4 = (f % 20) * 4;
        int gr = row0 + rr;
        if (gr < n) {
            int gbi = sbidx[rr];
            float4 q  = *(const float4*)(w + gbi * D + k4);
            float4 xv = *(const float4*)(x + (size_t)gr * D + k4);
            float d0 = __fsub_rn(q.x, xv.x), d1 = __fsub_rn(q.y, xv.y);
            float d2 = __fsub_rn(q.z, xv.z), d3 = __fsub_rn(q.w, xv.w);
            float4 o;
            o.x = __fadd_rn(xv.x, d0); o.y = __fadd_rn(xv.y, d1);
            o.z = __fadd_rn(xv.z, d2); o.w = __fadd_rn(xv.w, d3);
            *(float4*)(out + (size_t)gr * D + k4) = o;
            ss += (double)__fmul_rn(d0, d0) + (double)__fmul_rn(d1, d1);
            ss += (double)__fmul_rn(d2, d2) + (double)__fmul_rn(d3, d3);
        }
    }
#pragma unroll
    for (int off = 32; off > 0; off >>= 1) ss += __shfl_down(ss, off);
    int wid = threadIdx.x >> 6;
    if ((threadIdx.x & 63) == 0) bsum[wid] = ss;
    __syncthreads();
    if (threadIdx.x == 0)
        atomicAdd(loss_acc, bsum[0] + bsum[1] + bsum[2] + bsum[3]);
}

__global__ void vq_fin_kernel(const double* __restrict__ acc,
                              float* __restrict__ out_loss,
                              double count) {
    float m = (float)(*acc / count);
    *out_loss = __fadd_rn(m, __fmul_rn(0.25f, m));
}

// ---------------- fallback (ws too small): round-2 exact path ---------------
__global__ __launch_bounds__(64)
__attribute__((amdgpu_waves_per_eu(2, 2)))
void vq_main_exact(const float* __restrict__ x, const float* __restrict__ w,
                   const float* __restrict__ en, const float* __restrict__ ec,
                   float* __restrict__ out, double* __restrict__ loss_acc, int n) {
    const int r = blockIdx.x * 64 + threadIdx.x;
    double ss = 0.0;
    if (r < n) {
        float X[D];
        const float4* x4 = (const float4*)(x + (size_t)r * D);
#pragma unroll
        for (int i = 0; i < D / 4; ++i) {
            float4 v = x4[i];
            X[4 * i + 0] = v.x; X[4 * i + 1] = v.y;
            X[4 * i + 2] = v.z; X[4 * i + 3] = v.w;
        }
        float pr[8];
#pragma unroll
        for (int t = 0; t < 8; ++t) pr[t] = __fmul_rn(X[t], X[t]);
#pragma unroll
        for (int base = 8; base < D; base += 8)
#pragma unroll
            for (int t = 0; t < 8; ++t)
                pr[t] = __fadd_rn(pr[t], __fmul_rn(X[base + t], X[base + t]));
        float A = __fadd_rn(
            __fadd_rn(__fadd_rn(pr[0], pr[1]), __fadd_rn(pr[2], pr[3])),
            __fadd_rn(__fadd_rn(pr[4], pr[5]), __fadd_rn(pr[6], pr[7])));
        float best = 3.4e38f; int bi = 0;
        for (int j = 0; j < NE; ++j) {
            const float* ej = en + j * D;
            float d = 0.f;
#pragma unroll
            for (int k = 0; k < D; ++k) d = __builtin_fmaf(X[k], ej[k], d);
            float s = __fadd_rn(__fsub_rn(A, __fmul_rn(2.0f, d)), ec[j]);
            if (s < best) { best = s; bi = j; }
        }
        const float* wj = w + bi * D;
        float4* o4 = (float4*)(out + (size_t)r * D);
#pragma unroll
        for (int i = 0; i < D / 4; ++i) {
            float q0 = wj[4*i+0], q1 = wj[4*i+1], q2 = wj[4*i+2], q3 = wj[4*i+3];
            float d0 = __fsub_rn(q0, X[4*i+0]), d1 = __fsub_rn(q1, X[4*i+1]);
            float d2 = __fsub_rn(q2, X[4*i+2]), d3 = __fsub_rn(q3, X[4*i+3]);
            float4 o;
            o.x = __fadd_rn(X[4*i+0], d0); o.y = __fadd_rn(X[4*i+1], d1);
            o.z = __fadd_rn(X[4*i+2], d2); o.w = __fadd_rn(X[4*i+3], d3);
            o4[i] = o;
            ss += (double)__fmul_rn(d0, d0) + (double)__fmul_rn(d1, d1);
            ss += (double)__fmul_rn(d2, d2) + (double)__fmul_rn(d3, d3);
        }
    }
#pragma unroll
    for (int off = 32; off > 0; off >>= 1) ss += __shfl_down(ss, off);
    if (threadIdx.x == 0) atomicAdd(loss_acc, ss);
}

extern "C" void kernel_launch(void* const* d_in, const int* in_sizes, int n_in,
                              void* d_out, int out_size, void* d_ws, size_t ws_size,
                              hipStream_t stream) {
    const float* x = (const float*)d_in[0];   // cnt_emb [64,2048,80]
    const float* w = (const float*)d_in[1];   // embed_weight [1024,80]
    float* out = (float*)d_out;
    int n = in_sizes[0] / D;                  // 131072 rows

    char* ws = (char*)d_ws;
    double* acc = (double*)(ws + OFF_ACC);
    float*  en  = (float*)(ws + OFF_EN);
    float*  ec  = (float*)(ws + OFF_EC);

    hipMemsetAsync(ws + OFF_ACC, 0, 64, stream);
    if (ws_size >= WS_NEED) {
        char*  enbT = ws + OFF_ENBT;
        int*   cnt  = (int*)(ws + OFF_CNT);
        unsigned short* list = (unsigned short*)(ws + OFF_LIST);
        hipMemsetAsync(cnt, 0, (size_t)n * 4, stream);
        vq_prep<<<(NE + 255) / 256, 256, 0, stream>>>(w, en, ec, enbT);
        vq_mfma<<<n / 128, 256, 0, stream>>>(x, enbT, cnt, list, n);
        vq_exact_epi<<<(n + 255) / 256, 256, 0, stream>>>(x, en, ec, cnt, list,
                                                          w, out, acc, n);
    } else {
        char* enbT_dummy = ws + OFF_EC + 4096;  // unused path scratch
        vq_prep<<<(NE + 255) / 256, 256, 0, stream>>>(w, en, ec, enbT_dummy);
        vq_main_exact<<<(n + 63) / 64, 64, 0, stream>>>(x, w, en, ec, out, acc, n);
    }
    vq_fin_kernel<<<1, 1, 0, stream>>>(acc, out + (size_t)n * D, (double)n * D);
}

// Round 19
// 151.261 us; speedup vs baseline: 5.2597x; 5.2597x over previous
//
#include <hip/hip_runtime.h>

#define D   80
#define NE  1024
#define HS  128               // embeddings per half-stage
#define NH  (NE / HS)         // 8 half-stages per phase
#define CAP 32
// MARGIN >= 2*delta_bf16 (~0.42 worst case) + |ec-1| drift (~1e-5)
#define MARGIN 0.5f

// ws layout (bytes):
#define OFF_ACC  0            // 64B   double loss accumulator
#define OFF_EN   64           // [NE][D] f32 normalized embed (exact, ref order)
#define OFF_EC   327744       // [NE]    f32 ||en||^2 (exact, ref order)
#define OFF_ENBT 331840       // [10][NE] 16B chunks: bf16(-2*en), chunk-major
#define OFF_CNT  1019968      // [n] int  candidate count per row
#define OFF_LIST 1544256      // [n][CAP] u16 candidate j's
#define WS_NEED  9932864

typedef __attribute__((ext_vector_type(8))) short  bf16x8;
typedef __attribute__((ext_vector_type(4))) float  f32x4;

static __device__ __forceinline__ short f2bf(float f) {   // RNE float->bf16
    unsigned u = __float_as_uint(f);
    return (short)((u + 0x7fffu + ((u >> 16) & 1u)) >> 16);
}

static __device__ __forceinline__ bf16x8 cvt8(const float* p) {
    float4 f0 = *(const float4*)p;
    float4 f1 = *(const float4*)(p + 4);
    bf16x8 a;
    a[0] = f2bf(f0.x); a[1] = f2bf(f0.y); a[2] = f2bf(f0.z); a[3] = f2bf(f0.w);
    a[4] = f2bf(f1.x); a[5] = f2bf(f1.y); a[6] = f2bf(f1.z); a[7] = f2bf(f1.w);
    return a;
}

// direct global->LDS DMA, 16B per lane (zero VGPR staging)
static __device__ __forceinline__ void gload_lds16(const void* g, void* l) {
    __builtin_amdgcn_global_load_lds(
        (const __attribute__((address_space(1))) unsigned int*)g,
        (__attribute__((address_space(3))) unsigned int*)l, 16, 0, 0);
}

// ---------------- prep: exact en/ec (bit-exact ref order) + enbT ------------
// enbT chunk-major: chunk c (bf16 k in [8c,8c+8)) of emb j at c*16384 + j*16.
__global__ __launch_bounds__(256) void vq_prep(const float* __restrict__ w,
                                               float* __restrict__ en,
                                               float* __restrict__ ec,
                                               char* __restrict__ enbT) {
    int j = blockIdx.x * blockDim.x + threadIdx.x;
    if (j >= NE) return;
    const float* wj = w + j * D;
    float s = __fmul_rn(wj[0], wj[0]);
    for (int k = 1; k < D; ++k) s = __fadd_rn(s, __fmul_rn(wj[k], wj[k]));
    float norm = __fsqrt_rn(s);
    float* ej = en + j * D;
    float c = 0.f;
    for (int k = 0; k < D; ++k) {
        float v = __fdiv_rn(wj[k], norm);
        ej[k] = v;
        float sq = __fmul_rn(v, v);
        c = (k == 0) ? sq : __fadd_rn(c, sq);  // sequential k-order like np
    }
    ec[j] = c;
    for (int cc = 0; cc < 10; ++cc) {
        bf16x8 b;
#pragma unroll
        for (int e = 0; e < 8; ++e)
            b[e] = f2bf(__fmul_rn(-2.0f, ej[cc * 8 + e]));
        *(bf16x8*)(enbT + cc * 16384 + j * 16) = b;
    }
}

// ---------------- MFMA filter: r13/r15/r17-proven two-phase 16x16x32 --------
// r18 lesson: 32x32x16 with extrapolated A/B layout produced degenerate
// candidate sets (cnt overflow -> universal full-scan fallback: absmax 0.0
// but 795us). Only the 16x16x32 layout is end-to-end verified here. Keep it.
__global__ __launch_bounds__(256)
__attribute__((amdgpu_waves_per_eu(4, 4)))
void vq_mfma(
        const float* __restrict__ x,
        const char* __restrict__ enbT,
        int* __restrict__ cnt,
        unsigned short* __restrict__ list,
        int n) {
    // 2 buffers x 10 chunks x 128 embs x 16B; within a buffer chunk-plane
    // stride is 2048 and slot*16 is linear (128*16 == 2048) -> DMA-legal dest.
    __shared__ __align__(16) char lds[2][20480];

    const int tid  = threadIdx.x;
    const int lane = tid & 63;
    const int wv   = tid >> 6;
    const int row0 = blockIdx.x * 128 + wv * 32;   // 32 rows per wave (2 tiles)
    const int l15  = lane & 15;
    const int lg   = lane >> 4;

    // A fragments, K=80: A2 zeroed for lg>=2 so the k80-95 pad contributes 0.
    bf16x8 A0[2], A1[2], A2[2];
#pragma unroll
    for (int rt = 0; rt < 2; ++rt) {
        const float* xr = x + (size_t)(row0 + rt * 16 + l15) * D;
        A0[rt] = cvt8(xr + lg * 8);
        A1[rt] = cvt8(xr + 32 + lg * 8);
        if (lg < 2) A2[rt] = cvt8(xr + 64 + lg * 8);
        else { bf16x8 z = {}; A2[rt] = z; }
    }

#define STAGE(b, h) do {                                                      \
        _Pragma("unroll")                                                     \
        for (int t = 0; t < 5; ++t) {                                         \
            int slot = tid + t * 256;                                         \
            gload_lds16(enbT + (size_t)(slot >> 7) * 16384 + (h) * 2048       \
                             + (slot & 127) * 16,                             \
                        &lds[b][0] + slot * 16);                              \
        }                                                                     \
    } while (0)

    float vmin[2][4];
#pragma unroll
    for (int rt = 0; rt < 2; ++rt)
#pragma unroll
        for (int r = 0; r < 4; ++r) vmin[rt][r] = 3.4e38f;

    // ================= phase A: min-only scan =================
    STAGE(0, 0);
    for (int h = 0; h < NH; ++h) {
        __syncthreads();                 // drains DMA(h); prior reads done
        if (h + 1 < NH) STAGE((h + 1) & 1, h + 1);   // lands during compute
        const char* buf = &lds[h & 1][0];
        for (int e16 = 0; e16 < 8; ++e16) {
            const char* base = buf + (e16 * 16 + l15) * 16;
            bf16x8 B0 = *(const bf16x8*)(base + lg * 2048);
            bf16x8 B1 = *(const bf16x8*)(base + (4 + lg) * 2048);
            bf16x8 B2 = *(const bf16x8*)(base + (8 + (lg & 1)) * 2048);
#pragma unroll
            for (int rt = 0; rt < 2; ++rt) {
                f32x4 c = {0.f, 0.f, 0.f, 0.f};
                c = __builtin_amdgcn_mfma_f32_16x16x32_bf16(A0[rt], B0, c, 0, 0, 0);
                c = __builtin_amdgcn_mfma_f32_16x16x32_bf16(A1[rt], B1, c, 0, 0, 0);
                c = __builtin_amdgcn_mfma_f32_16x16x32_bf16(A2[rt], B2, c, 0, 0, 0);
#pragma unroll
                for (int r = 0; r < 4; ++r) vmin[rt][r] = fminf(vmin[rt][r], c[r]);
            }
        }
    }

    // final threshold: reduce across the 16-lane group sharing each row
    float thr[2][4];
#pragma unroll
    for (int rt = 0; rt < 2; ++rt)
#pragma unroll
        for (int r = 0; r < 4; ++r) {
            float v = vmin[rt][r];
#pragma unroll
            for (int m = 1; m < 16; m <<= 1) v = fminf(v, __shfl_xor(v, m));
            thr[rt][r] = v + MARGIN;
        }

    // ================= phase B: re-scan, capture candidates =================
    STAGE(0, 0);                         // safe: all buf0 phase-A reads done
    for (int h = 0; h < NH; ++h) {
        __syncthreads();
        if (h + 1 < NH) STAGE((h + 1) & 1, h + 1);
        const char* buf = &lds[h & 1][0];
        for (int e16 = 0; e16 < 8; ++e16) {
            const char* base = buf + (e16 * 16 + l15) * 16;
            bf16x8 B0 = *(const bf16x8*)(base + lg * 2048);
            bf16x8 B1 = *(const bf16x8*)(base + (4 + lg) * 2048);
            bf16x8 B2 = *(const bf16x8*)(base + (8 + (lg & 1)) * 2048);
            int jj = h * HS + e16 * 16 + l15;
#pragma unroll
            for (int rt = 0; rt < 2; ++rt) {
                f32x4 c = {0.f, 0.f, 0.f, 0.f};
                c = __builtin_amdgcn_mfma_f32_16x16x32_bf16(A0[rt], B0, c, 0, 0, 0);
                c = __builtin_amdgcn_mfma_f32_16x16x32_bf16(A1[rt], B1, c, 0, 0, 0);
                c = __builtin_amdgcn_mfma_f32_16x16x32_bf16(A2[rt], B2, c, 0, 0, 0);
                bool h0 = c[0] <= thr[rt][0], h1 = c[1] <= thr[rt][1];
                bool h2 = c[2] <= thr[rt][2], h3 = c[3] <= thr[rt][3];
                if (__any(h0 | h1 | h2 | h3)) {   // C layout: col=l15, row=lg*4+r
#pragma unroll
                    for (int r = 0; r < 4; ++r) {
                        bool hh = (r == 0) ? h0 : (r == 1) ? h1 : (r == 2) ? h2 : h3;
                        if (hh) {
                            int row = row0 + rt * 16 + lg * 4 + r;
                            int o = atomicAdd(cnt + row, 1);
                            if (o < CAP)
                                list[(size_t)row * CAP + o] = (unsigned short)jj;
                        }
                    }
                }
            }
        }
    }
#undef STAGE
}

// ---------- fused exact + epilogue (r13-proven cfg + r16-proven c==1 path) --
// waves_per_eu(1,2) -> VGPR 88, X[80] resident (r14 lesson: do not touch).
// c==1 fast path: two-phase candidate set provably contains the exact argmin,
// so a singleton IS the argmin -> skip X load, ||x||^2 and scoring (~half of
// rows at ~1.6 candidates/row avg).
__global__ __launch_bounds__(256)
__attribute__((amdgpu_waves_per_eu(1, 2)))
void vq_exact_epi(const float* __restrict__ x,
                  const float* __restrict__ en,
                  const float* __restrict__ ec,
                  const int* __restrict__ cnt,
                  const unsigned short* __restrict__ list,
                  const float* __restrict__ w,
                  float* __restrict__ out,
                  double* __restrict__ loss_acc, int n) {
    __shared__ int sbidx[256];
    __shared__ double bsum[4];
    const int row = blockIdx.x * 256 + threadIdx.x;

    int bi = 0;
    if (row < n) {
        int c = cnt[row];                       // issue early: gates everything
        if (c == 1) {
            bi = list[(size_t)row * CAP];       // singleton superset == argmin
        } else {
            float X[D];
            const float4* x4 = (const float4*)(x + (size_t)row * D);
#pragma unroll
            for (int i = 0; i < D / 4; ++i) {
                float4 v = x4[i];
                X[4 * i + 0] = v.x; X[4 * i + 1] = v.y;
                X[4 * i + 2] = v.z; X[4 * i + 3] = v.w;
            }
            // A = ||x||^2, numpy pairwise 8-accumulator pattern
            float pr[8];
#pragma unroll
            for (int t = 0; t < 8; ++t) pr[t] = __fmul_rn(X[t], X[t]);
#pragma unroll
            for (int base = 8; base < D; base += 8)
#pragma unroll
                for (int t = 0; t < 8; ++t)
                    pr[t] = __fadd_rn(pr[t], __fmul_rn(X[base + t], X[base + t]));
            float A = __fadd_rn(
                __fadd_rn(__fadd_rn(pr[0], pr[1]), __fadd_rn(pr[2], pr[3])),
                __fadd_rn(__fadd_rn(pr[4], pr[5]), __fadd_rn(pr[6], pr[7])));

            float best = 3.4e38f;
            bi = -1;
            if (c >= 2 && c <= CAP) {
                for (int i = 0; i < c; ++i) {
                    int j = list[(size_t)row * CAP + i];
                    const float* ej = en + j * D;
                    float d = 0.f;
#pragma unroll
                    for (int k = 0; k < D; ++k) d = __builtin_fmaf(X[k], ej[k], d);
                    float s = __fadd_rn(__fsub_rn(A, __fmul_rn(2.0f, d)), ec[j]);
                    // strict < plus lowest-j on exact tie == first-index rule
                    if (s < best || (s == best && j < bi)) { best = s; bi = j; }
                }
            } else {  // overflow / empty (never expected): exact full scan
                for (int j = 0; j < NE; ++j) {
                    const float* ej = en + j * D;
                    float d = 0.f;
#pragma unroll
                    for (int k = 0; k < D; ++k) d = __builtin_fmaf(X[k], ej[k], d);
                    float s = __fadd_rn(__fsub_rn(A, __fmul_rn(2.0f, d)), ec[j]);
                    if (s < best) { best = s; bi = j; }
                }
            }
        }
    }
    sbidx[threadIdx.x] = bi;
    __syncthreads();

    // epilogue: 256 rows cooperative, coalesced (proven r3 pattern)
    const int row0 = blockIdx.x * 256;
    double ss = 0.0;
#pragma unroll
    for (int t = 0; t < 20; ++t) {
        int f  = threadIdx.x + t * 256;        // 5120 = 256 rows x 20 float4
        int rr = f / 20;
        int k4 = (f % 20) * 4;
        int gr = row0 + rr;
        if (gr < n) {
            int gbi = sbidx[rr];
            float4 q  = *(const float4*)(w + gbi * D + k4);
            float4 xv = *(const float4*)(x + (size_t)gr * D + k4);
            float d0 = __fsub_rn(q.x, xv.x), d1 = __fsub_rn(q.y, xv.y);
            float d2 = __fsub_rn(q.z, xv.z), d3 = __fsub_rn(q.w, xv.w);
            float4 o;
            o.x = __fadd_rn(xv.x, d0); o.y = __fadd_rn(xv.y, d1);
            o.z = __fadd_rn(xv.z, d2); o.w = __fadd_rn(xv.w, d3);
            *(float4*)(out + (size_t)gr * D + k4) = o;
            ss += (double)__fmul_rn(d0, d0) + (double)__fmul_rn(d1, d1);
            ss += (double)__fmul_rn(d2, d2) + (double)__fmul_rn(d3, d3);
        }
    }
#pragma unroll
    for (int off = 32; off > 0; off >>= 1) ss += __shfl_down(ss, off);
    int wid = threadIdx.x >> 6;
    if ((threadIdx.x & 63) == 0) bsum[wid] = ss;
    __syncthreads();
    if (threadIdx.x == 0)
        atomicAdd(loss_acc, bsum[0] + bsum[1] + bsum[2] + bsum[3]);
}

__global__ void vq_fin_kernel(const double* __restrict__ acc,
                              float* __restrict__ out_loss,
                              double count) {
    float m = (float)(*acc / count);
    *out_loss = __fadd_rn(m, __fmul_rn(0.25f, m));
}

// ---------------- fallback (ws too small): round-2 exact path ---------------
__global__ __launch_bounds__(64)
__attribute__((amdgpu_waves_per_eu(2, 2)))
void vq_main_exact(const float* __restrict__ x, const float* __restrict__ w,
                   const float* __restrict__ en, const float* __restrict__ ec,
                   float* __restrict__ out, double* __restrict__ loss_acc, int n) {
    const int r = blockIdx.x * 64 + threadIdx.x;
    double ss = 0.0;
    if (r < n) {
        float X[D];
        const float4* x4 = (const float4*)(x + (size_t)r * D);
#pragma unroll
        for (int i = 0; i < D / 4; ++i) {
            float4 v = x4[i];
            X[4 * i + 0] = v.x; X[4 * i + 1] = v.y;
            X[4 * i + 2] = v.z; X[4 * i + 3] = v.w;
        }
        float pr[8];
#pragma unroll
        for (int t = 0; t < 8; ++t) pr[t] = __fmul_rn(X[t], X[t]);
#pragma unroll
        for (int base = 8; base < D; base += 8)
#pragma unroll
            for (int t = 0; t < 8; ++t)
                pr[t] = __fadd_rn(pr[t], __fmul_rn(X[base + t], X[base + t]));
        float A = __fadd_rn(
            __fadd_rn(__fadd_rn(pr[0], pr[1]), __fadd_rn(pr[2], pr[3])),
            __fadd_rn(__fadd_rn(pr[4], pr[5]), __fadd_rn(pr[6], pr[7])));
        float best = 3.4e38f; int bi = 0;
        for (int j = 0; j < NE; ++j) {
            const float* ej = en + j * D;
            float d = 0.f;
#pragma unroll
            for (int k = 0; k < D; ++k) d = __builtin_fmaf(X[k], ej[k], d);
            float s = __fadd_rn(__fsub_rn(A, __fmul_rn(2.0f, d)), ec[j]);
            if (s < best) { best = s; bi = j; }
        }
        const float* wj = w + bi * D;
        float4* o4 = (float4*)(out + (size_t)r * D);
#pragma unroll
        for (int i = 0; i < D / 4; ++i) {
            float q0 = wj[4*i+0], q1 = wj[4*i+1], q2 = wj[4*i+2], q3 = wj[4*i+3];
            float d0 = __fsub_rn(q0, X[4*i+0]), d1 = __fsub_rn(q1, X[4*i+1]);
            float d2 = __fsub_rn(q2, X[4*i+2]), d3 = __fsub_rn(q3, X[4*i+3]);
            float4 o;
            o.x = __fadd_rn(X[4*i+0], d0); o.y = __fadd_rn(X[4*i+1], d1);
            o.z = __fadd_rn(X[4*i+2], d2); o.w = __fadd_rn(X[4*i+3], d3);
            o4[i] = o;
            ss += (double)__fmul_rn(d0, d0) + (double)__fmul_rn(d1, d1);
            ss += (double)__fmul_rn(d2, d2) + (double)__fmul_rn(d3, d3);
        }
    }
#pragma unroll
    for (int off = 32; off > 0; off >>= 1) ss += __shfl_down(ss, off);
    if (threadIdx.x == 0) atomicAdd(loss_acc, ss);
}

extern "C" void kernel_launch(void* const* d_in, const int* in_sizes, int n_in,
                              void* d_out, int out_size, void* d_ws, size_t ws_size,
                              hipStream_t stream) {
    const float* x = (const float*)d_in[0];   // cnt_emb [64,2048,80]
    const float* w = (const float*)d_in[1];   // embed_weight [1024,80]
    float* out = (float*)d_out;
    int n = in_sizes[0] / D;                  // 131072 rows

    char* ws = (char*)d_ws;
    double* acc = (double*)(ws + OFF_ACC);
    float*  en  = (float*)(ws + OFF_EN);
    float*  ec  = (float*)(ws + OFF_EC);

    hipMemsetAsync(ws + OFF_ACC, 0, 64, stream);
    if (ws_size >= WS_NEED) {
        char*  enbT = ws + OFF_ENBT;
        int*   cnt  = (int*)(ws + OFF_CNT);
        unsigned short* list = (unsigned short*)(ws + OFF_LIST);
        hipMemsetAsync(cnt, 0, (size_t)n * 4, stream);
        vq_prep<<<(NE + 255) / 256, 256, 0, stream>>>(w, en, ec, enbT);
        vq_mfma<<<n / 128, 256, 0, stream>>>(x, enbT, cnt, list, n);
        vq_exact_epi<<<(n + 255) / 256, 256, 0, stream>>>(x, en, ec, cnt, list,
                                                          w, out, acc, n);
    } else {
        char* enbT_dummy = ws + OFF_EC + 4096;  // unused path scratch
        vq_prep<<<(NE + 255) / 256, 256, 0, stream>>>(w, en, ec, enbT_dummy);
        vq_main_exact<<<(n + 63) / 64, 64, 0, stream>>>(x, w, en, ec, out, acc, n);
    }
    vq_fin_kernel<<<1, 1, 0, stream>>>(acc, out + (size_t)n * D, (double)n * D);
}